// Round 3
// baseline (13810.840 us; speedup 1.0000x reference)
//
#include <hip/hip_runtime.h>

// ---------------------------------------------------------------------------
// Self_RNN forward, MI355X.
//   Wrv = Wrec@Wv ; Wrk = Wrec@Wk ; Wrq = Wrec@Wq ; Wkq = Wrk@Wrq^T
//   WgT = Wrk@Wq^T ; G[b,t] = x[b,t]@WgT^T ; XV[b,t] = x[b,t]@Wv
//   per step: y = h @ [Wrv | Wkq]  -> Vh = y[0:512], q = y[512:1024]
//             s0=(q.h)sc, s1=(h.G[t-1])sc, s2=(h.G[t])sc ; a=softmax(s)
//             h' = a0*Vh + a1*XV[t-1] + a2*XV[t]
// Sequential phase: 512 cooperative WGs = 32 chain-pairs x 16 column-slices.
// Weights LDS-resident (transposed Wt[1024][512] f16, 64 rows/WG, swizzled).
// One agent-scope atomic barrier per step; ybuf double-buffered by parity.
// ---------------------------------------------------------------------------

typedef _Float16 f16;
typedef _Float16 half8 __attribute__((ext_vector_type(8)));
typedef _Float16 h2 __attribute__((ext_vector_type(2)));
typedef float floatx4 __attribute__((ext_vector_type(4)));

#define AM_F32 0
#define AM_F16 1
#define BM_NN_F32 0   // B  is [K][N] f32 (transpose-staged)
#define BM_BT_F16 1   // Bt is [N][K] f16
#define BM_BT_F32 2   // Bt is [N][K] f32

#if defined(__has_builtin)
#if __has_builtin(__builtin_amdgcn_fdot2)
#define HAS_FDOT2 1
#endif
#endif

__device__ inline float dot2f(h2 a, h2 b, float c) {
#ifdef HAS_FDOT2
  return __builtin_amdgcn_fdot2(a, b, c, false);
#else
  return c + (float)a[0] * (float)b[0] + (float)a[1] * (float)b[1];
#endif
}

// C[M,N] = A[M,K] @ B ; 128x128 tile, BK=32, 4 waves, MFMA f16.
// CT=0: C[row*ldc + coff + col]   CT=1: C[(coff+col)*ldc + row]
template<int AMODE, int BMODE, int CT>
__global__ __launch_bounds__(256)
void gemm128(const void* __restrict__ Ap, const void* __restrict__ Bp,
             f16* __restrict__ C, int K, int ldbnn, long ldc, long coff,
             int ntiles) {
  __shared__ f16 Al[128 * 32];
  __shared__ f16 Bl[128 * 32];
  const int tid = threadIdx.x;
  const int lane = tid & 63;
  const int wid = tid >> 6;
  const int wr = wid >> 1, wc = wid & 1;
  const int mt = blockIdx.x / ntiles, nt = blockIdx.x % ntiles;
  const long m0 = (long)mt * 128, n0 = (long)nt * 128;

  floatx4 acc[4][4];
#pragma unroll
  for (int m = 0; m < 4; ++m)
#pragma unroll
    for (int n = 0; n < 4; ++n) acc[m][n] = (floatx4){0.f, 0.f, 0.f, 0.f};

  for (int k0 = 0; k0 < K; k0 += 32) {
    __syncthreads();
#pragma unroll
    for (int i = 0; i < 2; ++i) {
      const int slot = i * 256 + tid;
      const int row = slot >> 2;
      const int kc = (slot & 3) * 8;
      if constexpr (AMODE == AM_F16) {
        const f16* Ag = (const f16*)Ap;
        half8 v = *(const half8*)(Ag + (m0 + row) * (long)K + k0 + kc);
        *(half8*)(Al + slot * 8) = v;
      } else {
        const float* Ag = (const float*)Ap;
        const float* p = Ag + (m0 + row) * (long)K + k0 + kc;
        float4 v0 = *(const float4*)(p);
        float4 v1 = *(const float4*)(p + 4);
        half8 h;
        h[0] = (f16)v0.x; h[1] = (f16)v0.y; h[2] = (f16)v0.z; h[3] = (f16)v0.w;
        h[4] = (f16)v1.x; h[5] = (f16)v1.y; h[6] = (f16)v1.z; h[7] = (f16)v1.w;
        *(half8*)(Al + slot * 8) = h;
      }
    }
    if constexpr (BMODE == BM_NN_F32) {
      const float* Bg = (const float*)Bp;
      const int nn = tid & 127;
      const int kh = (tid >> 7) * 16;
#pragma unroll
      for (int j = 0; j < 16; j += 2) {
        float b0 = Bg[(long)(k0 + kh + j) * ldbnn + n0 + nn];
        float b1 = Bg[(long)(k0 + kh + j + 1) * ldbnn + n0 + nn];
        h2 hv; hv[0] = (f16)b0; hv[1] = (f16)b1;
        *(h2*)(Bl + nn * 32 + kh + j) = hv;
      }
    } else {
#pragma unroll
      for (int i = 0; i < 2; ++i) {
        const int slot = i * 256 + tid;
        const int row = slot >> 2;
        const int kc = (slot & 3) * 8;
        if constexpr (BMODE == BM_BT_F16) {
          const f16* Bg = (const f16*)Bp;
          half8 v = *(const half8*)(Bg + (n0 + row) * (long)K + k0 + kc);
          *(half8*)(Bl + slot * 8) = v;
        } else {
          const float* Bg = (const float*)Bp;
          const float* p = Bg + (n0 + row) * (long)K + k0 + kc;
          float4 v0 = *(const float4*)(p);
          float4 v1 = *(const float4*)(p + 4);
          half8 h;
          h[0] = (f16)v0.x; h[1] = (f16)v0.y; h[2] = (f16)v0.z; h[3] = (f16)v0.w;
          h[4] = (f16)v1.x; h[5] = (f16)v1.y; h[6] = (f16)v1.z; h[7] = (f16)v1.w;
          *(half8*)(Bl + slot * 8) = h;
        }
      }
    }
    __syncthreads();
    const int frow = lane & 15;
    const int fkc = (lane >> 4) * 8;
    half8 af[4], bf[4];
#pragma unroll
    for (int m = 0; m < 4; ++m)
      af[m] = *(const half8*)(Al + (wr * 64 + m * 16 + frow) * 32 + fkc);
#pragma unroll
    for (int n = 0; n < 4; ++n)
      bf[n] = *(const half8*)(Bl + (wc * 64 + n * 16 + frow) * 32 + fkc);
#pragma unroll
    for (int m = 0; m < 4; ++m)
#pragma unroll
      for (int n = 0; n < 4; ++n)
        acc[m][n] = __builtin_amdgcn_mfma_f32_16x16x32_f16(af[m], bf[n],
                                                           acc[m][n], 0, 0, 0);
  }
  const int crow = (lane >> 4) * 4;
  const int ccol = lane & 15;
#pragma unroll
  for (int m = 0; m < 4; ++m)
#pragma unroll
    for (int n = 0; n < 4; ++n)
#pragma unroll
      for (int r = 0; r < 4; ++r) {
        long row = m0 + wr * 64 + m * 16 + crow + r;
        long col = n0 + wc * 64 + n * 16 + ccol;
        if constexpr (CT)
          C[(coff + col) * ldc + row] = (f16)acc[m][n][r];
        else
          C[row * ldc + coff + col] = (f16)acc[m][n][r];
      }
}

__global__ void initbar(unsigned* bar) {
  if (threadIdx.x < 32)
    __hip_atomic_store(bar + threadIdx.x, 0u, __ATOMIC_RELAXED,
                       __HIP_MEMORY_SCOPE_AGENT);
}

// 512 WGs: wg = s*32 + cp. cp = chain-pair (chains 2cp, 2cp+1), s = slice
// (y-cols [s*64, s*64+64)). Same (wg & 31) => same XCD under %8 round-robin.
__global__ __launch_bounds__(256, 2)
void seq_kernel(const f16* __restrict__ Wt, const f16* __restrict__ GXV,
                float* __restrict__ ybuf, unsigned* __restrict__ bar,
                float* __restrict__ out) {
  const int wg = blockIdx.x;
  const int cp = wg & 31;
  const int s = wg >> 5;
  const int tid = threadIdx.x;
  const int T = 512;

  __shared__ __align__(16) char wlds[64 * 1024];   // 64 rows x 512 f16, swizzled
  __shared__ float yred[16][2][68];
  __shared__ h2 hpk[2][256];                       // h as f16 u-pairs
  __shared__ float swred[4][6];

  // ---- preload weight slice into LDS (swizzled 16B slots) ----
  {
    const int r = tid >> 2;                  // local row 0..63
    const int cb = (tid & 3) * 256;          // byte base within row
    const unsigned key = ((unsigned)(r >> 2) & 7u) << 4;
    const f16* src = Wt + (size_t)(s * 64 + r) * 512;
#pragma unroll
    for (int k = 0; k < 16; ++k) {
      half8 v = *(const half8*)((const char*)src + cb + k * 16);
      *(half8*)(wlds + r * 1024 + ((unsigned)(cb + k * 16) ^ key)) = v;
    }
  }
  // init h = 0
  float hr[2][2] = {{0.f, 0.f}, {0.f, 0.f}};
  {
    h2 z; z[0] = (f16)0.f; z[1] = (f16)0.f;
    hpk[0][tid] = z; hpk[1][tid] = z;
  }
  __syncthreads();

  const int cg = tid & 15;        // col group: 4 local cols
  const int p = tid >> 4;         // u-part: u in [p*32, p*32+32)
  const unsigned cgx = ((unsigned)cg & 7u) << 4;
  const float scale = 0.04419417382415922f;  // 1/sqrt(512)
  const long ch0 = (long)cp * 2;

  for (int t = 0; t < T; ++t) {
    const int par = t & 1;
    // ---- matvec partials: 4 cols x 32 u's x 2 chains ----
    half8 ha[2][4];
#pragma unroll
    for (int g = 0; g < 2; ++g)
#pragma unroll
      for (int k4 = 0; k4 < 4; ++k4)
        ha[g][k4] = *(const half8*)&hpk[g][p * 16 + k4 * 4];
    float acc[4][2];
#pragma unroll
    for (int j = 0; j < 4; ++j) { acc[j][0] = 0.f; acc[j][1] = 0.f; }
#pragma unroll
    for (int j = 0; j < 4; ++j) {
      const char* rowb = wlds + (cg * 4 + j) * 1024;
#pragma unroll
      for (int k4 = 0; k4 < 4; ++k4) {
        half8 w = *(const half8*)(rowb + ((unsigned)(p * 64 + k4 * 16) ^ cgx));
#pragma unroll
        for (int e = 0; e < 4; ++e) {
          h2 wp; wp[0] = w[2 * e]; wp[1] = w[2 * e + 1];
#pragma unroll
          for (int g = 0; g < 2; ++g) {
            h2 hp; hp[0] = ha[g][k4][2 * e]; hp[1] = ha[g][k4][2 * e + 1];
            acc[j][g] = dot2f(wp, hp, acc[j][g]);
          }
        }
      }
    }
#pragma unroll
    for (int j = 0; j < 4; ++j) {
      yred[p][0][cg * 4 + j] = acc[j][0];
      yred[p][1][cg * 4 + j] = acc[j][1];
    }
    __syncthreads();

    // ---- reduce over 16 u-parts, publish slice to ybuf (agent scope) ----
    if (tid < 128) {
      const int g = tid >> 6, c = tid & 63;
      float sum = 0.f;
#pragma unroll
      for (int p16 = 0; p16 < 16; ++p16) sum += yred[p16][g][c];
      float* dst = ybuf + (((size_t)cp * 2 + par) * 2 + g) * 1024 + s * 64 + c;
      __hip_atomic_store(dst, sum, __ATOMIC_RELAXED, __HIP_MEMORY_SCOPE_AGENT);
    }
    __syncthreads();

    // ---- one barrier per step ----
    if (tid == 0) {
      __hip_atomic_fetch_add(bar + cp, 1u, __ATOMIC_RELEASE,
                             __HIP_MEMORY_SCOPE_AGENT);
      const unsigned tgt = 16u * (unsigned)(t + 1);
      while (__hip_atomic_load(bar + cp, __ATOMIC_RELAXED,
                               __HIP_MEMORY_SCOPE_AGENT) < tgt) {}
      (void)__hip_atomic_load(bar + cp, __ATOMIC_ACQUIRE,
                              __HIP_MEMORY_SCOPE_AGENT);
    }
    __syncthreads();

    // ---- gather full y, score dot partials (u = 2tid, 2tid+1) ----
    float vh[2][2], qq[2][2], pr[6];
#pragma unroll
    for (int g = 0; g < 2; ++g) {
      const float* yb = ybuf + (((size_t)cp * 2 + par) * 2 + g) * 1024;
      vh[g][0] = __hip_atomic_load(yb + 2 * tid, __ATOMIC_RELAXED,
                                   __HIP_MEMORY_SCOPE_AGENT);
      vh[g][1] = __hip_atomic_load(yb + 2 * tid + 1, __ATOMIC_RELAXED,
                                   __HIP_MEMORY_SCOPE_AGENT);
      qq[g][0] = __hip_atomic_load(yb + 512 + 2 * tid, __ATOMIC_RELAXED,
                                   __HIP_MEMORY_SCOPE_AGENT);
      qq[g][1] = __hip_atomic_load(yb + 512 + 2 * tid + 1, __ATOMIC_RELAXED,
                                   __HIP_MEMORY_SCOPE_AGENT);
      const f16* rowc = GXV + ((ch0 + g) * T + t) * 1024;
      h2 gc = *(const h2*)(rowc + 2 * tid);
      h2 gp; gp[0] = (f16)0.f; gp[1] = (f16)0.f;
      if (t > 0) gp = *(const h2*)(rowc - 1024 + 2 * tid);
      pr[g * 3 + 0] = qq[g][0] * hr[g][0] + qq[g][1] * hr[g][1];
      pr[g * 3 + 1] = (float)gp[0] * hr[g][0] + (float)gp[1] * hr[g][1];
      pr[g * 3 + 2] = (float)gc[0] * hr[g][0] + (float)gc[1] * hr[g][1];
    }
#pragma unroll
    for (int off = 32; off > 0; off >>= 1)
#pragma unroll
      for (int i = 0; i < 6; ++i) pr[i] += __shfl_down(pr[i], off);
    if ((tid & 63) == 0) {
#pragma unroll
      for (int i = 0; i < 6; ++i) swred[tid >> 6][i] = pr[i];
    }
    __syncthreads();

    // ---- redundant softmax + h update (all threads, all WGs identical) ----
    float sv[6];
#pragma unroll
    for (int i = 0; i < 6; ++i)
      sv[i] = (swred[0][i] + swred[1][i] + swred[2][i] + swred[3][i]) * scale;
#pragma unroll
    for (int g = 0; g < 2; ++g) {
      float s0 = sv[g * 3 + 0], s1 = sv[g * 3 + 1], s2 = sv[g * 3 + 2];
      float mx = fmaxf(s0, fmaxf(s1, s2));
      float e0 = __expf(s0 - mx), e1 = __expf(s1 - mx), e2 = __expf(s2 - mx);
      float inv = 1.f / (e0 + e1 + e2);
      float a0 = e0 * inv, a1 = e1 * inv, a2 = e2 * inv;
      const f16* rowc = GXV + ((ch0 + g) * T + t) * 1024;
      h2 xc = *(const h2*)(rowc + 512 + 2 * tid);
      h2 xp; xp[0] = (f16)0.f; xp[1] = (f16)0.f;
      if (t > 0) xp = *(const h2*)(rowc - 1024 + 512 + 2 * tid);
      hr[g][0] = a0 * vh[g][0] + a1 * (float)xp[0] + a2 * (float)xc[0];
      hr[g][1] = a0 * vh[g][1] + a1 * (float)xp[1] + a2 * (float)xc[1];
      h2 hn; hn[0] = (f16)hr[g][0]; hn[1] = (f16)hr[g][1];
      hpk[g][tid] = hn;
      if (t == T - 1 && s == 0) {
        out[(ch0 + g) * 512 + 2 * tid] = hr[g][0];
        out[(ch0 + g) * 512 + 2 * tid + 1] = hr[g][1];
      }
    }
    __syncthreads();
  }
}

extern "C" void kernel_launch(void* const* d_in, const int* in_sizes, int n_in,
                              void* d_out, int out_size, void* d_ws,
                              size_t ws_size, hipStream_t stream) {
  const float* x = (const float*)d_in[0];     // [64][512][512]
  const float* Wq = (const float*)d_in[1];
  const float* Wk = (const float*)d_in[2];
  const float* Wv = (const float*)d_in[3];
  const float* Wrec = (const float*)d_in[4];
  float* out = (float*)d_out;                 // [64][512]

  char* ws = (char*)d_ws;
  f16* GXV = (f16*)ws;                        // [32768][1024] f16 = 64 MiB
  f16* Wt = (f16*)(ws + 67108864);            // [1024][512] f16 = 1 MiB
  f16* Wrk = (f16*)(ws + 68157440);           // 512 KiB
  f16* Wrq = (f16*)(ws + 68681728);           // 512 KiB (ybuf overlays later)
  f16* WgT = (f16*)(ws + 69206016);           // 512 KiB (bar overlays later)
  float* ybuf = (float*)(ws + 68681728);      // [32][2][2][1024] f32 = 512 KiB
  unsigned* bar = (unsigned*)(ws + 69206016); // 32 counters

  // ---- weight combinations ----
  gemm128<AM_F32, BM_NN_F32, 0><<<16, 256, 0, stream>>>(Wrec, Wk, Wrk, 512, 512, 512, 0, 4);
  gemm128<AM_F32, BM_NN_F32, 0><<<16, 256, 0, stream>>>(Wrec, Wq, Wrq, 512, 512, 512, 0, 4);
  // Wt rows 0..511  = Wrv^T
  gemm128<AM_F32, BM_NN_F32, 1><<<16, 256, 0, stream>>>(Wrec, Wv, Wt, 512, 512, 512, 0, 4);
  // Wt rows 512..1023 = Wkq^T  (Wkq = Wrk@Wrq^T)
  gemm128<AM_F16, BM_BT_F16, 1><<<16, 256, 0, stream>>>(Wrk, Wrq, Wt, 512, 0, 512, 512, 4);
  // WgT = Wrk@Wq^T
  gemm128<AM_F16, BM_BT_F32, 0><<<16, 256, 0, stream>>>(Wrk, Wq, WgT, 512, 0, 512, 0, 4);
  // G and XV for all (b,t)
  gemm128<AM_F32, BM_BT_F16, 0><<<1024, 256, 0, stream>>>(x, WgT, GXV, 512, 0, 1024, 0, 4);
  gemm128<AM_F32, BM_NN_F32, 0><<<1024, 256, 0, stream>>>(x, Wv, GXV, 512, 512, 1024, 512, 4);

  initbar<<<1, 64, 0, stream>>>(bar);

  // ---- sequential recurrence: cooperative, 512 WGs (2/CU guaranteed) ----
  const f16* WtC = Wt; const f16* GXVC = GXV;
  void* args[] = {(void*)&WtC, (void*)&GXVC, (void*)&ybuf, (void*)&bar, (void*)&out};
  dim3 grid(512), block(256);
  if (hipLaunchCooperativeKernel((const void*)seq_kernel, grid, block, args, 0,
                                 stream) != hipSuccess) {
    seq_kernel<<<grid, block, 0, stream>>>(WtC, GXVC, ybuf, bar, out);
  }
}

// Round 4
// 10642.715 us; speedup vs baseline: 1.2977x; 1.2977x over previous
//
#include <hip/hip_runtime.h>

// ---------------------------------------------------------------------------
// Self_RNN forward, MI355X.
//   Wrv = Wrec@Wv ; Wrk = Wrec@Wk ; Wrq = Wrec@Wq ; Wkq = Wrk@Wrq^T
//   WgT = Wrk@Wq^T ; G[b,t] = x[b,t]@WgT^T ; XV[b,t] = x[b,t]@Wv
//   per step: y = h @ [Wrv | Wkq]  -> Vh = y[0:512], q = y[512:1024]
//             s0=(q.h)sc, s1=(h.G[t-1])sc, s2=(h.G[t])sc ; a=softmax(s)
//             h' = a0*Vh + a1*XV[t-1] + a2*XV[t]
// Sequential phase: 512 cooperative WGs = 32 chain-pairs x 16 column-slices.
// Weights LDS-resident. Barrier = per-slice padded release-flags (no RMW)
// + wave-parallel polling. ybuf double-buffered by step parity; monotonic
// flags make the parity reuse race-free.
// ---------------------------------------------------------------------------

typedef _Float16 f16;
typedef _Float16 half8 __attribute__((ext_vector_type(8)));
typedef _Float16 h2 __attribute__((ext_vector_type(2)));
typedef float floatx4 __attribute__((ext_vector_type(4)));
typedef unsigned long long u64;

#define AM_F32 0
#define AM_F16 1
#define BM_NN_F32 0   // B  is [K][N] f32 (transpose-staged)
#define BM_BT_F16 1   // Bt is [N][K] f16
#define BM_BT_F32 2   // Bt is [N][K] f32

#if defined(__has_builtin)
#if __has_builtin(__builtin_amdgcn_fdot2)
#define HAS_FDOT2 1
#endif
#endif

__device__ inline float dot2f(h2 a, h2 b, float c) {
#ifdef HAS_FDOT2
  return __builtin_amdgcn_fdot2(a, b, c, false);
#else
  return c + (float)a[0] * (float)b[0] + (float)a[1] * (float)b[1];
#endif
}

// C[M,N] = A[M,K] @ B ; 128x128 tile, BK=32, 4 waves, MFMA f16.
// CT=0: C[row*ldc + coff + col]   CT=1: C[(coff+col)*ldc + row]
template<int AMODE, int BMODE, int CT>
__global__ __launch_bounds__(256)
void gemm128(const void* __restrict__ Ap, const void* __restrict__ Bp,
             f16* __restrict__ C, int K, int ldbnn, long ldc, long coff,
             int ntiles) {
  __shared__ f16 Al[128 * 32];
  __shared__ f16 Bl[128 * 32];
  const int tid = threadIdx.x;
  const int lane = tid & 63;
  const int wid = tid >> 6;
  const int wr = wid >> 1, wc = wid & 1;
  const int mt = blockIdx.x / ntiles, nt = blockIdx.x % ntiles;
  const long m0 = (long)mt * 128, n0 = (long)nt * 128;

  floatx4 acc[4][4];
#pragma unroll
  for (int m = 0; m < 4; ++m)
#pragma unroll
    for (int n = 0; n < 4; ++n) acc[m][n] = (floatx4){0.f, 0.f, 0.f, 0.f};

  for (int k0 = 0; k0 < K; k0 += 32) {
    __syncthreads();
#pragma unroll
    for (int i = 0; i < 2; ++i) {
      const int slot = i * 256 + tid;
      const int row = slot >> 2;
      const int kc = (slot & 3) * 8;
      if constexpr (AMODE == AM_F16) {
        const f16* Ag = (const f16*)Ap;
        half8 v = *(const half8*)(Ag + (m0 + row) * (long)K + k0 + kc);
        *(half8*)(Al + slot * 8) = v;
      } else {
        const float* Ag = (const float*)Ap;
        const float* p = Ag + (m0 + row) * (long)K + k0 + kc;
        float4 v0 = *(const float4*)(p);
        float4 v1 = *(const float4*)(p + 4);
        half8 h;
        h[0] = (f16)v0.x; h[1] = (f16)v0.y; h[2] = (f16)v0.z; h[3] = (f16)v0.w;
        h[4] = (f16)v1.x; h[5] = (f16)v1.y; h[6] = (f16)v1.z; h[7] = (f16)v1.w;
        *(half8*)(Al + slot * 8) = h;
      }
    }
    if constexpr (BMODE == BM_NN_F32) {
      const float* Bg = (const float*)Bp;
      const int nn = tid & 127;
      const int kh = (tid >> 7) * 16;
#pragma unroll
      for (int j = 0; j < 16; j += 2) {
        float b0 = Bg[(long)(k0 + kh + j) * ldbnn + n0 + nn];
        float b1 = Bg[(long)(k0 + kh + j + 1) * ldbnn + n0 + nn];
        h2 hv; hv[0] = (f16)b0; hv[1] = (f16)b1;
        *(h2*)(Bl + nn * 32 + kh + j) = hv;
      }
    } else {
#pragma unroll
      for (int i = 0; i < 2; ++i) {
        const int slot = i * 256 + tid;
        const int row = slot >> 2;
        const int kc = (slot & 3) * 8;
        if constexpr (BMODE == BM_BT_F16) {
          const f16* Bg = (const f16*)Bp;
          half8 v = *(const half8*)(Bg + (n0 + row) * (long)K + k0 + kc);
          *(half8*)(Bl + slot * 8) = v;
        } else {
          const float* Bg = (const float*)Bp;
          const float* p = Bg + (n0 + row) * (long)K + k0 + kc;
          float4 v0 = *(const float4*)(p);
          float4 v1 = *(const float4*)(p + 4);
          half8 h;
          h[0] = (f16)v0.x; h[1] = (f16)v0.y; h[2] = (f16)v0.z; h[3] = (f16)v0.w;
          h[4] = (f16)v1.x; h[5] = (f16)v1.y; h[6] = (f16)v1.z; h[7] = (f16)v1.w;
          *(half8*)(Bl + slot * 8) = h;
        }
      }
    }
    __syncthreads();
    const int frow = lane & 15;
    const int fkc = (lane >> 4) * 8;
    half8 af[4], bf[4];
#pragma unroll
    for (int m = 0; m < 4; ++m)
      af[m] = *(const half8*)(Al + (wr * 64 + m * 16 + frow) * 32 + fkc);
#pragma unroll
    for (int n = 0; n < 4; ++n)
      bf[n] = *(const half8*)(Bl + (wc * 64 + n * 16 + frow) * 32 + fkc);
#pragma unroll
    for (int m = 0; m < 4; ++m)
#pragma unroll
      for (int n = 0; n < 4; ++n)
        acc[m][n] = __builtin_amdgcn_mfma_f32_16x16x32_f16(af[m], bf[n],
                                                           acc[m][n], 0, 0, 0);
  }
  const int crow = (lane >> 4) * 4;
  const int ccol = lane & 15;
#pragma unroll
  for (int m = 0; m < 4; ++m)
#pragma unroll
    for (int n = 0; n < 4; ++n)
#pragma unroll
      for (int r = 0; r < 4; ++r) {
        long row = m0 + wr * 64 + m * 16 + crow + r;
        long col = n0 + wc * 64 + n * 16 + ccol;
        if constexpr (CT)
          C[(coff + col) * ldc + row] = (f16)acc[m][n][r];
        else
          C[row * ldc + coff + col] = (f16)acc[m][n][r];
      }
}

// zero the 32 KiB flag region (visibility via kernel boundary)
__global__ void initbar(unsigned* flags) {
  flags[blockIdx.x * 256 + threadIdx.x] = 0u;
}

// 512 WGs: wg = s*32 + cp. cp = chain-pair (chains 2cp, 2cp+1), s = slice
// (y-cols [s*64, s*64+64)). flag[(cp*16+s)*16]: one 64B line per slice.
__global__ __launch_bounds__(256, 2)
void seq_kernel(const f16* __restrict__ Wt, const f16* __restrict__ GXV,
                float* __restrict__ ybuf, unsigned* __restrict__ flags,
                float* __restrict__ out) {
  const int wg = blockIdx.x;
  const int cp = wg & 31;
  const int s = wg >> 5;
  const int tid = threadIdx.x;
  const int T = 512;

  __shared__ __align__(16) char wlds[64 * 1024];   // 64 rows x 512 f16, swizzled
  __shared__ float yred[16][2][68];
  __shared__ h2 hpk[2][256];                       // h as f16 u-pairs
  __shared__ float swred[4][6];

  // ---- preload weight slice into LDS (swizzled 16B slots) ----
  {
    const int r = tid >> 2;                  // local row 0..63
    const int cb = (tid & 3) * 256;          // byte base within row
    const unsigned key = ((unsigned)(r >> 2) & 7u) << 4;
    const f16* src = Wt + (size_t)(s * 64 + r) * 512;
#pragma unroll
    for (int k = 0; k < 16; ++k) {
      half8 v = *(const half8*)((const char*)src + cb + k * 16);
      *(half8*)(wlds + r * 1024 + ((unsigned)(cb + k * 16) ^ key)) = v;
    }
  }
  float hr[2][2] = {{0.f, 0.f}, {0.f, 0.f}};
  {
    h2 z; z[0] = (f16)0.f; z[1] = (f16)0.f;
    hpk[0][tid] = z; hpk[1][tid] = z;
  }
  __syncthreads();

  const int cg = tid & 15;        // col group: 4 local cols
  const int p = tid >> 4;         // u-part: u in [p*32, p*32+32)
  const unsigned cgx = ((unsigned)cg & 7u) << 4;
  const float scale = 0.04419417382415922f;  // 1/sqrt(512)
  const long ch0 = (long)cp * 2;
  const int lane = tid & 63;

  for (int t = 0; t < T; ++t) {
    const int par = t & 1;
    // ---- matvec partials: 4 cols x 32 u's x 2 chains ----
    half8 ha[2][4];
#pragma unroll
    for (int g = 0; g < 2; ++g)
#pragma unroll
      for (int k4 = 0; k4 < 4; ++k4)
        ha[g][k4] = *(const half8*)&hpk[g][p * 16 + k4 * 4];
    float acc[4][2];
#pragma unroll
    for (int j = 0; j < 4; ++j) { acc[j][0] = 0.f; acc[j][1] = 0.f; }
#pragma unroll
    for (int j = 0; j < 4; ++j) {
      const char* rowb = wlds + (cg * 4 + j) * 1024;
#pragma unroll
      for (int k4 = 0; k4 < 4; ++k4) {
        half8 w = *(const half8*)(rowb + ((unsigned)(p * 64 + k4 * 16) ^ cgx));
#pragma unroll
        for (int e = 0; e < 4; ++e) {
          h2 wp; wp[0] = w[2 * e]; wp[1] = w[2 * e + 1];
#pragma unroll
          for (int g = 0; g < 2; ++g) {
            h2 hp; hp[0] = ha[g][k4][2 * e]; hp[1] = ha[g][k4][2 * e + 1];
            acc[j][g] = dot2f(wp, hp, acc[j][g]);
          }
        }
      }
    }
#pragma unroll
    for (int j = 0; j < 4; ++j) {
      yred[p][0][cg * 4 + j] = acc[j][0];
      yred[p][1][cg * 4 + j] = acc[j][1];
    }
    __syncthreads();

    // ---- reduce over 16 u-parts, publish slice to ybuf (agent scope) ----
    if (tid < 128) {
      const int g = tid >> 6, c = tid & 63;
      float sum = 0.f;
#pragma unroll
      for (int p16 = 0; p16 < 16; ++p16) sum += yred[p16][g][c];
      float* dst = ybuf + (((size_t)cp * 2 + par) * 2 + g) * 1024 + s * 64 + c;
      __hip_atomic_store(dst, sum, __ATOMIC_RELAXED, __HIP_MEMORY_SCOPE_AGENT);
    }
    __syncthreads();   // all publish stores drained (vmcnt0 per wave) pre-flag

    // ---- barrier: per-slice release flag + wave-parallel poll ----
    if (tid == 0)
      __hip_atomic_store(flags + ((unsigned)(cp * 16 + s)) * 16u,
                         (unsigned)(t + 1), __ATOMIC_RELEASE,
                         __HIP_MEMORY_SCOPE_AGENT);
    {
      const unsigned tgt = (unsigned)(t + 1);
      if (lane < 16) {
        const unsigned* fa = flags + ((unsigned)(cp * 16 + lane)) * 16u;
        while (__hip_atomic_load(fa, __ATOMIC_RELAXED,
                                 __HIP_MEMORY_SCOPE_AGENT) < tgt)
          __builtin_amdgcn_s_sleep(1);
      }
      // ordering + cache-invalidate: one acquire load per wave
      (void)__hip_atomic_load(flags + ((unsigned)(cp * 16 + (lane & 15))) * 16u,
                              __ATOMIC_ACQUIRE, __HIP_MEMORY_SCOPE_AGENT);
    }

    // ---- gather y (64-bit coherent loads), score dot partials ----
    float vh[2][2], pr[6];
#pragma unroll
    for (int g = 0; g < 2; ++g) {
      const float* yb = ybuf + (((size_t)cp * 2 + par) * 2 + g) * 1024;
      u64 rv = __hip_atomic_load((const u64*)(yb + 2 * tid), __ATOMIC_RELAXED,
                                 __HIP_MEMORY_SCOPE_AGENT);
      u64 rq = __hip_atomic_load((const u64*)(yb + 512 + 2 * tid),
                                 __ATOMIC_RELAXED, __HIP_MEMORY_SCOPE_AGENT);
      vh[g][0] = __uint_as_float((unsigned)(rv & 0xffffffffu));
      vh[g][1] = __uint_as_float((unsigned)(rv >> 32));
      float q0 = __uint_as_float((unsigned)(rq & 0xffffffffu));
      float q1 = __uint_as_float((unsigned)(rq >> 32));
      const f16* rowc = GXV + ((ch0 + g) * T + t) * 1024;
      h2 gc = *(const h2*)(rowc + 2 * tid);
      h2 gp; gp[0] = (f16)0.f; gp[1] = (f16)0.f;
      if (t > 0) gp = *(const h2*)(rowc - 1024 + 2 * tid);
      pr[g * 3 + 0] = q0 * hr[g][0] + q1 * hr[g][1];
      pr[g * 3 + 1] = (float)gp[0] * hr[g][0] + (float)gp[1] * hr[g][1];
      pr[g * 3 + 2] = (float)gc[0] * hr[g][0] + (float)gc[1] * hr[g][1];
    }
#pragma unroll
    for (int off = 32; off > 0; off >>= 1)
#pragma unroll
      for (int i = 0; i < 6; ++i) pr[i] += __shfl_down(pr[i], off);
    if ((tid & 63) == 0) {
#pragma unroll
      for (int i = 0; i < 6; ++i) swred[tid >> 6][i] = pr[i];
    }
    __syncthreads();

    // ---- redundant softmax + h update (all threads, all WGs identical) ----
    float sv[6];
#pragma unroll
    for (int i = 0; i < 6; ++i)
      sv[i] = (swred[0][i] + swred[1][i] + swred[2][i] + swred[3][i]) * scale;
#pragma unroll
    for (int g = 0; g < 2; ++g) {
      float s0 = sv[g * 3 + 0], s1 = sv[g * 3 + 1], s2 = sv[g * 3 + 2];
      float mx = fmaxf(s0, fmaxf(s1, s2));
      float e0 = __expf(s0 - mx), e1 = __expf(s1 - mx), e2 = __expf(s2 - mx);
      float inv = 1.f / (e0 + e1 + e2);
      float a0 = e0 * inv, a1 = e1 * inv, a2 = e2 * inv;
      const f16* rowc = GXV + ((ch0 + g) * T + t) * 1024;
      h2 xc = *(const h2*)(rowc + 512 + 2 * tid);
      h2 xp; xp[0] = (f16)0.f; xp[1] = (f16)0.f;
      if (t > 0) xp = *(const h2*)(rowc - 1024 + 512 + 2 * tid);
      hr[g][0] = a0 * vh[g][0] + a1 * (float)xp[0] + a2 * (float)xc[0];
      hr[g][1] = a0 * vh[g][1] + a1 * (float)xp[1] + a2 * (float)xc[1];
      h2 hn; hn[0] = (f16)hr[g][0]; hn[1] = (f16)hr[g][1];
      hpk[g][tid] = hn;
      if (t == T - 1 && s == 0) {
        out[(ch0 + g) * 512 + 2 * tid] = hr[g][0];
        out[(ch0 + g) * 512 + 2 * tid + 1] = hr[g][1];
      }
    }
    __syncthreads();
  }
}

extern "C" void kernel_launch(void* const* d_in, const int* in_sizes, int n_in,
                              void* d_out, int out_size, void* d_ws,
                              size_t ws_size, hipStream_t stream) {
  const float* x = (const float*)d_in[0];     // [64][512][512]
  const float* Wq = (const float*)d_in[1];
  const float* Wk = (const float*)d_in[2];
  const float* Wv = (const float*)d_in[3];
  const float* Wrec = (const float*)d_in[4];
  float* out = (float*)d_out;                 // [64][512]

  char* ws = (char*)d_ws;
  f16* GXV = (f16*)ws;                        // [32768][1024] f16 = 64 MiB
  f16* Wt = (f16*)(ws + 67108864);            // [1024][512] f16 = 1 MiB
  f16* Wrk = (f16*)(ws + 68157440);           // 512 KiB
  f16* Wrq = (f16*)(ws + 68681728);           // 512 KiB (ybuf overlays later)
  f16* WgT = (f16*)(ws + 69206016);           // 512 KiB (flags overlay later)
  float* ybuf = (float*)(ws + 68681728);      // [32][2][2][1024] f32 = 512 KiB
  unsigned* flags = (unsigned*)(ws + 69206016); // 32 cp x 16 slices x 64B = 32KB

  // ---- weight combinations ----
  gemm128<AM_F32, BM_NN_F32, 0><<<16, 256, 0, stream>>>(Wrec, Wk, Wrk, 512, 512, 512, 0, 4);
  gemm128<AM_F32, BM_NN_F32, 0><<<16, 256, 0, stream>>>(Wrec, Wq, Wrq, 512, 512, 512, 0, 4);
  // Wt rows 0..511  = Wrv^T
  gemm128<AM_F32, BM_NN_F32, 1><<<16, 256, 0, stream>>>(Wrec, Wv, Wt, 512, 512, 512, 0, 4);
  // Wt rows 512..1023 = Wkq^T  (Wkq = Wrk@Wrq^T)
  gemm128<AM_F16, BM_BT_F16, 1><<<16, 256, 0, stream>>>(Wrk, Wrq, Wt, 512, 0, 512, 512, 4);
  // WgT = Wrk@Wq^T
  gemm128<AM_F16, BM_BT_F32, 0><<<16, 256, 0, stream>>>(Wrk, Wq, WgT, 512, 0, 512, 0, 4);
  // G and XV for all (b,t)
  gemm128<AM_F32, BM_BT_F16, 0><<<1024, 256, 0, stream>>>(x, WgT, GXV, 512, 0, 1024, 0, 4);
  gemm128<AM_F32, BM_NN_F32, 0><<<1024, 256, 0, stream>>>(x, Wv, GXV, 512, 512, 1024, 512, 4);

  initbar<<<32, 256, 0, stream>>>(flags);

  // ---- sequential recurrence: cooperative, 512 WGs (2/CU guaranteed) ----
  const f16* WtC = Wt; const f16* GXVC = GXV;
  void* args[] = {(void*)&WtC, (void*)&GXVC, (void*)&ybuf, (void*)&flags, (void*)&out};
  dim3 grid(512), block(256);
  if (hipLaunchCooperativeKernel((const void*)seq_kernel, grid, block, args, 0,
                                 stream) != hipSuccess) {
    seq_kernel<<<grid, block, 0, stream>>>(WtC, GXVC, ybuf, flags, out);
  }
}

// Round 5
// 2475.373 us; speedup vs baseline: 5.5793x; 4.2994x over previous
//
#include <hip/hip_runtime.h>

// ---------------------------------------------------------------------------
// Self_RNN forward, MI355X.
//   Wrv = Wrec@Wv ; Wrk = Wrec@Wk ; Wrq = Wrec@Wq ; Wkq = Wrk@Wrq^T
//   WgT = Wrk@Wq^T ; G[b,t] = x[b,t]@WgT^T ; XV[b,t] = x[b,t]@Wv
//   per step: y = h @ [Wrv | Wkq]  -> Vh = y[0:512], q = y[512:1024]
//             s0=(q.h)sc, s1=(h.G[t-1])sc, s2=(h.G[t])sc ; a=softmax(s)
//             h' = a0*Vh + a1*XV[t-1] + a2*XV[t]
// Sequential phase: 512 cooperative WGs = 32 chain-pairs x 16 column-slices.
// Weights LDS-resident. Sync = TAGGED DATA: each y element published as
// u64 {tag=t+1, f32}; consumers poll the words themselves. One agent-scope
// hop per step, no fences/invalidate. ybuf parity double-buffered (safe by
// tag monotonicity + program order); re-zeroed each launch.
// ---------------------------------------------------------------------------

typedef _Float16 f16;
typedef _Float16 half8 __attribute__((ext_vector_type(8)));
typedef _Float16 h2 __attribute__((ext_vector_type(2)));
typedef float floatx4 __attribute__((ext_vector_type(4)));
typedef unsigned long long u64;

#define AM_F32 0
#define AM_F16 1
#define BM_NN_F32 0   // B  is [K][N] f32 (transpose-staged)
#define BM_BT_F16 1   // Bt is [N][K] f16
#define BM_BT_F32 2   // Bt is [N][K] f32

#if defined(__has_builtin)
#if __has_builtin(__builtin_amdgcn_fdot2)
#define HAS_FDOT2 1
#endif
#endif

__device__ inline float dot2f(h2 a, h2 b, float c) {
#ifdef HAS_FDOT2
  return __builtin_amdgcn_fdot2(a, b, c, false);
#else
  return c + (float)a[0] * (float)b[0] + (float)a[1] * (float)b[1];
#endif
}

// C[M,N] = A[M,K] @ B ; 128x128 tile, BK=32, 4 waves, MFMA f16.
// CT=0: C[row*ldc + coff + col]   CT=1: C[(coff+col)*ldc + row]
template<int AMODE, int BMODE, int CT>
__global__ __launch_bounds__(256)
void gemm128(const void* __restrict__ Ap, const void* __restrict__ Bp,
             f16* __restrict__ C, int K, int ldbnn, long ldc, long coff,
             int ntiles) {
  __shared__ f16 Al[128 * 32];
  __shared__ f16 Bl[128 * 32];
  const int tid = threadIdx.x;
  const int lane = tid & 63;
  const int wid = tid >> 6;
  const int wr = wid >> 1, wc = wid & 1;
  const int mt = blockIdx.x / ntiles, nt = blockIdx.x % ntiles;
  const long m0 = (long)mt * 128, n0 = (long)nt * 128;

  floatx4 acc[4][4];
#pragma unroll
  for (int m = 0; m < 4; ++m)
#pragma unroll
    for (int n = 0; n < 4; ++n) acc[m][n] = (floatx4){0.f, 0.f, 0.f, 0.f};

  for (int k0 = 0; k0 < K; k0 += 32) {
    __syncthreads();
#pragma unroll
    for (int i = 0; i < 2; ++i) {
      const int slot = i * 256 + tid;
      const int row = slot >> 2;
      const int kc = (slot & 3) * 8;
      if constexpr (AMODE == AM_F16) {
        const f16* Ag = (const f16*)Ap;
        half8 v = *(const half8*)(Ag + (m0 + row) * (long)K + k0 + kc);
        *(half8*)(Al + slot * 8) = v;
      } else {
        const float* Ag = (const float*)Ap;
        const float* p = Ag + (m0 + row) * (long)K + k0 + kc;
        float4 v0 = *(const float4*)(p);
        float4 v1 = *(const float4*)(p + 4);
        half8 h;
        h[0] = (f16)v0.x; h[1] = (f16)v0.y; h[2] = (f16)v0.z; h[3] = (f16)v0.w;
        h[4] = (f16)v1.x; h[5] = (f16)v1.y; h[6] = (f16)v1.z; h[7] = (f16)v1.w;
        *(half8*)(Al + slot * 8) = h;
      }
    }
    if constexpr (BMODE == BM_NN_F32) {
      const float* Bg = (const float*)Bp;
      const int nn = tid & 127;
      const int kh = (tid >> 7) * 16;
#pragma unroll
      for (int j = 0; j < 16; j += 2) {
        float b0 = Bg[(long)(k0 + kh + j) * ldbnn + n0 + nn];
        float b1 = Bg[(long)(k0 + kh + j + 1) * ldbnn + n0 + nn];
        h2 hv; hv[0] = (f16)b0; hv[1] = (f16)b1;
        *(h2*)(Bl + nn * 32 + kh + j) = hv;
      }
    } else {
#pragma unroll
      for (int i = 0; i < 2; ++i) {
        const int slot = i * 256 + tid;
        const int row = slot >> 2;
        const int kc = (slot & 3) * 8;
        if constexpr (BMODE == BM_BT_F16) {
          const f16* Bg = (const f16*)Bp;
          half8 v = *(const half8*)(Bg + (n0 + row) * (long)K + k0 + kc);
          *(half8*)(Bl + slot * 8) = v;
        } else {
          const float* Bg = (const float*)Bp;
          const float* p = Bg + (n0 + row) * (long)K + k0 + kc;
          float4 v0 = *(const float4*)(p);
          float4 v1 = *(const float4*)(p + 4);
          half8 h;
          h[0] = (f16)v0.x; h[1] = (f16)v0.y; h[2] = (f16)v0.z; h[3] = (f16)v0.w;
          h[4] = (f16)v1.x; h[5] = (f16)v1.y; h[6] = (f16)v1.z; h[7] = (f16)v1.w;
          *(half8*)(Bl + slot * 8) = h;
        }
      }
    }
    __syncthreads();
    const int frow = lane & 15;
    const int fkc = (lane >> 4) * 8;
    half8 af[4], bf[4];
#pragma unroll
    for (int m = 0; m < 4; ++m)
      af[m] = *(const half8*)(Al + (wr * 64 + m * 16 + frow) * 32 + fkc);
#pragma unroll
    for (int n = 0; n < 4; ++n)
      bf[n] = *(const half8*)(Bl + (wc * 64 + n * 16 + frow) * 32 + fkc);
#pragma unroll
    for (int m = 0; m < 4; ++m)
#pragma unroll
      for (int n = 0; n < 4; ++n)
        acc[m][n] = __builtin_amdgcn_mfma_f32_16x16x32_f16(af[m], bf[n],
                                                           acc[m][n], 0, 0, 0);
  }
  const int crow = (lane >> 4) * 4;
  const int ccol = lane & 15;
#pragma unroll
  for (int m = 0; m < 4; ++m)
#pragma unroll
    for (int n = 0; n < 4; ++n)
#pragma unroll
      for (int r = 0; r < 4; ++r) {
        long row = m0 + wr * 64 + m * 16 + crow + r;
        long col = n0 + wc * 64 + n * 16 + ccol;
        if constexpr (CT)
          C[(coff + col) * ldc + row] = (f16)acc[m][n][r];
        else
          C[row * ldc + coff + col] = (f16)acc[m][n][r];
      }
}

// zero the tagged y buffer (1 MiB = 131072 u64) — MUST run every launch
// (stale tags from a previous replay would satisfy the poll instantly).
__global__ void zero_ybuf(u64* ybuf) {
  ybuf[(size_t)blockIdx.x * 256 + threadIdx.x] = 0ull;
}

// 512 WGs: wg = s*32 + cp. cp = chain-pair (chains 2cp, 2cp+1), s = slice
// (publishes y-cols [s*64, s*64+64) for both chains, tagged with t+1).
__global__ __launch_bounds__(256, 2)
void seq_kernel(const f16* __restrict__ Wt, const f16* __restrict__ GXV,
                u64* __restrict__ ybuf, float* __restrict__ out) {
  const int wg = blockIdx.x;
  const int cp = wg & 31;
  const int s = wg >> 5;
  const int tid = threadIdx.x;
  const int T = 512;

  __shared__ __align__(16) char wlds[64 * 1024];   // 64 rows x 512 f16, swizzled
  __shared__ float yred[16][2][68];
  __shared__ h2 hpk[2][256];                       // h as f16 u-pairs
  __shared__ float swred[4][6];

  // ---- preload weight slice into LDS (swizzled 16B slots) ----
  {
    const int r = tid >> 2;                  // local row 0..63
    const int cb = (tid & 3) * 256;          // byte base within row
    const unsigned key = ((unsigned)(r >> 2) & 7u) << 4;
    const f16* src = Wt + (size_t)(s * 64 + r) * 512;
#pragma unroll
    for (int k = 0; k < 16; ++k) {
      half8 v = *(const half8*)((const char*)src + cb + k * 16);
      *(half8*)(wlds + r * 1024 + ((unsigned)(cb + k * 16) ^ key)) = v;
    }
  }
  float hr[2][2] = {{0.f, 0.f}, {0.f, 0.f}};
  {
    h2 z; z[0] = (f16)0.f; z[1] = (f16)0.f;
    hpk[0][tid] = z; hpk[1][tid] = z;
  }
  __syncthreads();

  const int cg = tid & 15;        // col group: 4 local cols
  const int p = tid >> 4;         // u-part: u in [p*32, p*32+32)
  const unsigned cgx = ((unsigned)cg & 7u) << 4;
  const float scale = 0.04419417382415922f;  // 1/sqrt(512)
  const long ch0 = (long)cp * 2;

  for (int t = 0; t < T; ++t) {
    const int par = t & 1;
    // ---- matvec partials: 4 cols x 32 u's x 2 chains ----
    half8 ha[2][4];
#pragma unroll
    for (int g = 0; g < 2; ++g)
#pragma unroll
      for (int k4 = 0; k4 < 4; ++k4)
        ha[g][k4] = *(const half8*)&hpk[g][p * 16 + k4 * 4];
    float acc[4][2];
#pragma unroll
    for (int j = 0; j < 4; ++j) { acc[j][0] = 0.f; acc[j][1] = 0.f; }
#pragma unroll
    for (int j = 0; j < 4; ++j) {
      const char* rowb = wlds + (cg * 4 + j) * 1024;
#pragma unroll
      for (int k4 = 0; k4 < 4; ++k4) {
        half8 w = *(const half8*)(rowb + ((unsigned)(p * 64 + k4 * 16) ^ cgx));
#pragma unroll
        for (int e = 0; e < 4; ++e) {
          h2 wp; wp[0] = w[2 * e]; wp[1] = w[2 * e + 1];
#pragma unroll
          for (int g = 0; g < 2; ++g) {
            h2 hp; hp[0] = ha[g][k4][2 * e]; hp[1] = ha[g][k4][2 * e + 1];
            acc[j][g] = dot2f(wp, hp, acc[j][g]);
          }
        }
      }
    }
#pragma unroll
    for (int j = 0; j < 4; ++j) {
      yred[p][0][cg * 4 + j] = acc[j][0];
      yred[p][1][cg * 4 + j] = acc[j][1];
    }
    __syncthreads();

    // ---- reduce 16 partials, publish TAGGED words (one hop, no fence) ----
    const u64 tagw = ((u64)(unsigned)(t + 1)) << 32;
    if (tid < 128) {
      const int g = tid >> 6, c = tid & 63;
      float sum = 0.f;
#pragma unroll
      for (int p16 = 0; p16 < 16; ++p16) sum += yred[p16][g][c];
      u64* dst = ybuf + ((size_t)cp * 4 + par * 2 + g) * 1024 + s * 64 + c;
      __hip_atomic_store(dst, tagw | (u64)__float_as_uint(sum),
                         __ATOMIC_RELAXED, __HIP_MEMORY_SCOPE_AGENT);
    }

    // ---- poll-gather this thread's 8 tagged words ----
    const u64* y0 = ybuf + ((size_t)cp * 4 + par * 2) * 1024;
    const u64* y1 = y0 + 1024;
    u64 w0, w1, w2, w3, w4, w5, w6, w7;
    for (;;) {
      w0 = __hip_atomic_load(y0 + 2 * tid, __ATOMIC_RELAXED, __HIP_MEMORY_SCOPE_AGENT);
      w1 = __hip_atomic_load(y0 + 2 * tid + 1, __ATOMIC_RELAXED, __HIP_MEMORY_SCOPE_AGENT);
      w2 = __hip_atomic_load(y0 + 512 + 2 * tid, __ATOMIC_RELAXED, __HIP_MEMORY_SCOPE_AGENT);
      w3 = __hip_atomic_load(y0 + 512 + 2 * tid + 1, __ATOMIC_RELAXED, __HIP_MEMORY_SCOPE_AGENT);
      w4 = __hip_atomic_load(y1 + 2 * tid, __ATOMIC_RELAXED, __HIP_MEMORY_SCOPE_AGENT);
      w5 = __hip_atomic_load(y1 + 2 * tid + 1, __ATOMIC_RELAXED, __HIP_MEMORY_SCOPE_AGENT);
      w6 = __hip_atomic_load(y1 + 512 + 2 * tid, __ATOMIC_RELAXED, __HIP_MEMORY_SCOPE_AGENT);
      w7 = __hip_atomic_load(y1 + 512 + 2 * tid + 1, __ATOMIC_RELAXED, __HIP_MEMORY_SCOPE_AGENT);
      if (w0 >= tagw && w1 >= tagw && w2 >= tagw && w3 >= tagw &&
          w4 >= tagw && w5 >= tagw && w6 >= tagw && w7 >= tagw)
        break;
      __builtin_amdgcn_s_sleep(1);
    }
    float vh[2][2];
    vh[0][0] = __uint_as_float((unsigned)w0);
    vh[0][1] = __uint_as_float((unsigned)w1);
    vh[1][0] = __uint_as_float((unsigned)w4);
    vh[1][1] = __uint_as_float((unsigned)w5);
    const float q00 = __uint_as_float((unsigned)w2);
    const float q01 = __uint_as_float((unsigned)w3);
    const float q10 = __uint_as_float((unsigned)w6);
    const float q11 = __uint_as_float((unsigned)w7);

    // ---- score dot partials (u = 2tid, 2tid+1) ----
    float pr[6];
#pragma unroll
    for (int g = 0; g < 2; ++g) {
      const f16* rowc = GXV + ((ch0 + g) * T + t) * 1024;
      h2 gc = *(const h2*)(rowc + 2 * tid);
      h2 gp; gp[0] = (f16)0.f; gp[1] = (f16)0.f;
      if (t > 0) gp = *(const h2*)(rowc - 1024 + 2 * tid);
      const float qa = g ? q10 : q00, qb = g ? q11 : q01;
      pr[g * 3 + 0] = qa * hr[g][0] + qb * hr[g][1];
      pr[g * 3 + 1] = (float)gp[0] * hr[g][0] + (float)gp[1] * hr[g][1];
      pr[g * 3 + 2] = (float)gc[0] * hr[g][0] + (float)gc[1] * hr[g][1];
    }
#pragma unroll
    for (int off = 32; off > 0; off >>= 1)
#pragma unroll
      for (int i = 0; i < 6; ++i) pr[i] += __shfl_down(pr[i], off);
    if ((tid & 63) == 0) {
#pragma unroll
      for (int i = 0; i < 6; ++i) swred[tid >> 6][i] = pr[i];
    }
    __syncthreads();

    // ---- redundant softmax + h update (all threads, all WGs identical) ----
    float sv[6];
#pragma unroll
    for (int i = 0; i < 6; ++i)
      sv[i] = (swred[0][i] + swred[1][i] + swred[2][i] + swred[3][i]) * scale;
#pragma unroll
    for (int g = 0; g < 2; ++g) {
      float s0 = sv[g * 3 + 0], s1 = sv[g * 3 + 1], s2 = sv[g * 3 + 2];
      float mx = fmaxf(s0, fmaxf(s1, s2));
      float e0 = __expf(s0 - mx), e1 = __expf(s1 - mx), e2 = __expf(s2 - mx);
      float inv = 1.f / (e0 + e1 + e2);
      float a0 = e0 * inv, a1 = e1 * inv, a2 = e2 * inv;
      const f16* rowc = GXV + ((ch0 + g) * T + t) * 1024;
      h2 xc = *(const h2*)(rowc + 512 + 2 * tid);
      h2 xp; xp[0] = (f16)0.f; xp[1] = (f16)0.f;
      if (t > 0) xp = *(const h2*)(rowc - 1024 + 512 + 2 * tid);
      hr[g][0] = a0 * vh[g][0] + a1 * (float)xp[0] + a2 * (float)xc[0];
      hr[g][1] = a0 * vh[g][1] + a1 * (float)xp[1] + a2 * (float)xc[1];
      h2 hn; hn[0] = (f16)hr[g][0]; hn[1] = (f16)hr[g][1];
      hpk[g][tid] = hn;
      if (t == T - 1 && s == 0) {
        out[(ch0 + g) * 512 + 2 * tid] = hr[g][0];
        out[(ch0 + g) * 512 + 2 * tid + 1] = hr[g][1];
      }
    }
    __syncthreads();
  }
}

extern "C" void kernel_launch(void* const* d_in, const int* in_sizes, int n_in,
                              void* d_out, int out_size, void* d_ws,
                              size_t ws_size, hipStream_t stream) {
  const float* x = (const float*)d_in[0];     // [64][512][512]
  const float* Wq = (const float*)d_in[1];
  const float* Wk = (const float*)d_in[2];
  const float* Wv = (const float*)d_in[3];
  const float* Wrec = (const float*)d_in[4];
  float* out = (float*)d_out;                 // [64][512]

  char* ws = (char*)d_ws;
  f16* GXV = (f16*)ws;                        // [32768][1024] f16 = 64 MiB
  f16* Wt = (f16*)(ws + 67108864);            // [1024][512] f16 = 1 MiB
  f16* Wrk = (f16*)(ws + 68157440);           // 512 KiB
  f16* Wrq = (f16*)(ws + 68681728);           // 512 KiB (ybuf overlays after use)
  f16* WgT = (f16*)(ws + 69206016);           // 512 KiB (ybuf overlays after use)
  u64* ybuf = (u64*)(ws + 68681728);          // [32][2][2][1024] u64 = 1 MiB

  // ---- weight combinations ----
  gemm128<AM_F32, BM_NN_F32, 0><<<16, 256, 0, stream>>>(Wrec, Wk, Wrk, 512, 512, 512, 0, 4);
  gemm128<AM_F32, BM_NN_F32, 0><<<16, 256, 0, stream>>>(Wrec, Wq, Wrq, 512, 512, 512, 0, 4);
  // Wt rows 0..511  = Wrv^T
  gemm128<AM_F32, BM_NN_F32, 1><<<16, 256, 0, stream>>>(Wrec, Wv, Wt, 512, 512, 512, 0, 4);
  // Wt rows 512..1023 = Wkq^T  (Wkq = Wrk@Wrq^T)
  gemm128<AM_F16, BM_BT_F16, 1><<<16, 256, 0, stream>>>(Wrk, Wrq, Wt, 512, 0, 512, 512, 4);
  // WgT = Wrk@Wq^T
  gemm128<AM_F16, BM_BT_F32, 0><<<16, 256, 0, stream>>>(Wrk, Wq, WgT, 512, 0, 512, 0, 4);
  // G and XV for all (b,t)
  gemm128<AM_F32, BM_BT_F16, 0><<<1024, 256, 0, stream>>>(x, WgT, GXV, 512, 0, 1024, 0, 4);
  gemm128<AM_F32, BM_NN_F32, 0><<<1024, 256, 0, stream>>>(x, Wv, GXV, 512, 512, 1024, 512, 4);

  // zero tagged buffer (after gemms that used the overlaid region)
  zero_ybuf<<<512, 256, 0, stream>>>(ybuf);

  // ---- sequential recurrence: cooperative, 512 WGs (2/CU guaranteed) ----
  const f16* WtC = Wt; const f16* GXVC = GXV;
  void* args[] = {(void*)&WtC, (void*)&GXVC, (void*)&ybuf, (void*)&out};
  dim3 grid(512), block(256);
  if (hipLaunchCooperativeKernel((const void*)seq_kernel, grid, block, args, 0,
                                 stream) != hipSuccess) {
    seq_kernel<<<grid, block, 0, stream>>>(WtC, GXVC, ybuf, out);
  }
}

// Round 6
// 1890.406 us; speedup vs baseline: 7.3058x; 1.3094x over previous
//
#include <hip/hip_runtime.h>

// ---------------------------------------------------------------------------
// Self_RNN forward, MI355X.
//   Wrv = Wrec@Wv ; Wrk = Wrec@Wk ; Wrq = Wrec@Wq ; Wkq = Wrk@Wrq^T
//   WgT = Wrk@Wq^T ; G[b,t] = x[b,t]@WgT^T ; XV[b,t] = x[b,t]@Wv
//   per step: y = h @ [Wrv | Wkq]  -> Vh = y[0:512], q = y[512:1024]
//             s0=(q.h)sc, s1=(h.G[t-1])sc, s2=(h.G[t])sc ; a=softmax(s)
//             h' = a0*Vh + a1*XV[t-1] + a2*XV[t]
// Sequential phase: 256 cooperative WGs = 16 groups (4 chains) x 16 slices,
// exactly 1 WG/CU. Weights LDS-resident (64 rows x 512 f16, swizzled).
// Sync = tagged u64 {tag=t+1, f32}. Vh slices publish 64 cols x 4 chains;
// q slices publish ONE s0-partial scalar per chain (q never leaves the WG).
// s1/s2 + GXV loads hoisted off the post-poll critical path.
// ---------------------------------------------------------------------------

typedef _Float16 f16;
typedef _Float16 half8 __attribute__((ext_vector_type(8)));
typedef _Float16 h2 __attribute__((ext_vector_type(2)));
typedef float floatx4 __attribute__((ext_vector_type(4)));
typedef unsigned long long u64;

#define AM_F32 0
#define AM_F16 1
#define BM_NN_F32 0   // B  is [K][N] f32 (transpose-staged)
#define BM_BT_F16 1   // Bt is [N][K] f16
#define BM_BT_F32 2   // Bt is [N][K] f32

#if defined(__has_builtin)
#if __has_builtin(__builtin_amdgcn_fdot2)
#define HAS_FDOT2 1
#endif
#endif

__device__ inline float dot2f(h2 a, h2 b, float c) {
#ifdef HAS_FDOT2
  return __builtin_amdgcn_fdot2(a, b, c, false);
#else
  return c + (float)a[0] * (float)b[0] + (float)a[1] * (float)b[1];
#endif
}

// C[M,N] = A[M,K] @ B ; 128x128 tile, BK=32, 4 waves, MFMA f16.
// CT=0: C[row*ldc + coff + col]   CT=1: C[(coff+col)*ldc + row]
template<int AMODE, int BMODE, int CT>
__global__ __launch_bounds__(256)
void gemm128(const void* __restrict__ Ap, const void* __restrict__ Bp,
             f16* __restrict__ C, int K, int ldbnn, long ldc, long coff,
             int ntiles) {
  __shared__ f16 Al[128 * 32];
  __shared__ f16 Bl[128 * 32];
  const int tid = threadIdx.x;
  const int lane = tid & 63;
  const int wid = tid >> 6;
  const int wr = wid >> 1, wc = wid & 1;
  const int mt = blockIdx.x / ntiles, nt = blockIdx.x % ntiles;
  const long m0 = (long)mt * 128, n0 = (long)nt * 128;

  floatx4 acc[4][4];
#pragma unroll
  for (int m = 0; m < 4; ++m)
#pragma unroll
    for (int n = 0; n < 4; ++n) acc[m][n] = (floatx4){0.f, 0.f, 0.f, 0.f};

  for (int k0 = 0; k0 < K; k0 += 32) {
    __syncthreads();
#pragma unroll
    for (int i = 0; i < 2; ++i) {
      const int slot = i * 256 + tid;
      const int row = slot >> 2;
      const int kc = (slot & 3) * 8;
      if constexpr (AMODE == AM_F16) {
        const f16* Ag = (const f16*)Ap;
        half8 v = *(const half8*)(Ag + (m0 + row) * (long)K + k0 + kc);
        *(half8*)(Al + slot * 8) = v;
      } else {
        const float* Ag = (const float*)Ap;
        const float* p = Ag + (m0 + row) * (long)K + k0 + kc;
        float4 v0 = *(const float4*)(p);
        float4 v1 = *(const float4*)(p + 4);
        half8 h;
        h[0] = (f16)v0.x; h[1] = (f16)v0.y; h[2] = (f16)v0.z; h[3] = (f16)v0.w;
        h[4] = (f16)v1.x; h[5] = (f16)v1.y; h[6] = (f16)v1.z; h[7] = (f16)v1.w;
        *(half8*)(Al + slot * 8) = h;
      }
    }
    if constexpr (BMODE == BM_NN_F32) {
      const float* Bg = (const float*)Bp;
      const int nn = tid & 127;
      const int kh = (tid >> 7) * 16;
#pragma unroll
      for (int j = 0; j < 16; j += 2) {
        float b0 = Bg[(long)(k0 + kh + j) * ldbnn + n0 + nn];
        float b1 = Bg[(long)(k0 + kh + j + 1) * ldbnn + n0 + nn];
        h2 hv; hv[0] = (f16)b0; hv[1] = (f16)b1;
        *(h2*)(Bl + nn * 32 + kh + j) = hv;
      }
    } else {
#pragma unroll
      for (int i = 0; i < 2; ++i) {
        const int slot = i * 256 + tid;
        const int row = slot >> 2;
        const int kc = (slot & 3) * 8;
        if constexpr (BMODE == BM_BT_F16) {
          const f16* Bg = (const f16*)Bp;
          half8 v = *(const half8*)(Bg + (n0 + row) * (long)K + k0 + kc);
          *(half8*)(Bl + slot * 8) = v;
        } else {
          const float* Bg = (const float*)Bp;
          const float* p = Bg + (n0 + row) * (long)K + k0 + kc;
          float4 v0 = *(const float4*)(p);
          float4 v1 = *(const float4*)(p + 4);
          half8 h;
          h[0] = (f16)v0.x; h[1] = (f16)v0.y; h[2] = (f16)v0.z; h[3] = (f16)v0.w;
          h[4] = (f16)v1.x; h[5] = (f16)v1.y; h[6] = (f16)v1.z; h[7] = (f16)v1.w;
          *(half8*)(Bl + slot * 8) = h;
        }
      }
    }
    __syncthreads();
    const int frow = lane & 15;
    const int fkc = (lane >> 4) * 8;
    half8 af[4], bf[4];
#pragma unroll
    for (int m = 0; m < 4; ++m)
      af[m] = *(const half8*)(Al + (wr * 64 + m * 16 + frow) * 32 + fkc);
#pragma unroll
    for (int n = 0; n < 4; ++n)
      bf[n] = *(const half8*)(Bl + (wc * 64 + n * 16 + frow) * 32 + fkc);
#pragma unroll
    for (int m = 0; m < 4; ++m)
#pragma unroll
      for (int n = 0; n < 4; ++n)
        acc[m][n] = __builtin_amdgcn_mfma_f32_16x16x32_f16(af[m], bf[n],
                                                           acc[m][n], 0, 0, 0);
  }
  const int crow = (lane >> 4) * 4;
  const int ccol = lane & 15;
#pragma unroll
  for (int m = 0; m < 4; ++m)
#pragma unroll
    for (int n = 0; n < 4; ++n)
#pragma unroll
      for (int r = 0; r < 4; ++r) {
        long row = m0 + wr * 64 + m * 16 + crow + r;
        long col = n0 + wc * 64 + n * 16 + ccol;
        if constexpr (CT)
          C[(coff + col) * ldc + row] = (f16)acc[m][n][r];
        else
          C[row * ldc + coff + col] = (f16)acc[m][n][r];
      }
}

// zero tagged buffer: 66560 u64 (yV 65536 + s0p 1024). MUST run every launch.
__global__ void zero_ybuf(u64* ybuf) {
  ybuf[(size_t)blockIdx.x * 256 + threadIdx.x] = 0ull;
}

// 256 WGs: wg = s*16 + grp. grp = chain group (chains 4grp..4grp+3),
// s = slice (y-cols [s*64, s*64+64)). wg%8 = grp%8 -> whole group on one XCD.
// ybuf: yV[16 grp][2 par][4 ch][512 col] u64 ; s0p = ybuf+65536:
// [16][2][4 ch][8 qslice] u64.
__global__ __launch_bounds__(256, 1)
void seq_kernel(const f16* __restrict__ Wt, const f16* __restrict__ GXV,
                u64* __restrict__ ybuf, float* __restrict__ out) {
  const int wg = blockIdx.x;
  const int grp = wg & 15;
  const int s = wg >> 4;
  const int tid = threadIdx.x;
  const int T = 512;

  __shared__ __align__(16) char wlds[64 * 1024];   // 64 rows x 512 f16, swizzled
  __shared__ float yred[16][4][68];
  __shared__ h2 hpk[4][256];                       // h as f16 u-pairs
  __shared__ float swred[4][8];
  __shared__ float svals[4];

  // ---- preload weight slice into LDS (swizzled 16B slots) ----
  {
    const int r = tid >> 2;                  // local row 0..63
    const int cb = (tid & 3) * 256;          // byte base within row
    const unsigned key = ((unsigned)(r >> 2) & 7u) << 4;
    const f16* src = Wt + (size_t)(s * 64 + r) * 512;
#pragma unroll
    for (int k = 0; k < 16; ++k) {
      half8 v = *(const half8*)((const char*)src + cb + k * 16);
      *(half8*)(wlds + r * 1024 + ((unsigned)(cb + k * 16) ^ key)) = v;
    }
  }
  {
    h2 z; z[0] = (f16)0.f; z[1] = (f16)0.f;
#pragma unroll
    for (int ch = 0; ch < 4; ++ch) hpk[ch][tid] = z;
  }
  __syncthreads();

  const int cg = tid & 15;        // col group: 4 local cols
  const int p = tid >> 4;         // u-part: u in [p*32, p*32+32)
  const unsigned cgx = ((unsigned)cg & 7u) << 4;
  const float scale = 0.04419417382415922f;  // 1/sqrt(512)
  const bool isV = (s < 8);
  u64* const yV = ybuf;
  u64* const s0p = ybuf + 65536;

  for (int t = 0; t < T; ++t) {
    const int par = t & 1;
    const u64 tagw = ((u64)(unsigned)(t + 1)) << 32;

    // ---- hoist all GXV loads for this step (fill latency under matvec) ----
    h2 gc4[4], gp4[4], xc4[4], xp4[4];
#pragma unroll
    for (int ch = 0; ch < 4; ++ch) {
      const f16* rowc = GXV + (((size_t)grp * 4 + ch) * T + t) * 1024;
      gc4[ch] = *(const h2*)(rowc + 2 * tid);
      xc4[ch] = *(const h2*)(rowc + 512 + 2 * tid);
      h2 z; z[0] = (f16)0.f; z[1] = (f16)0.f;
      gp4[ch] = z; xp4[ch] = z;
      if (t > 0) {
        gp4[ch] = *(const h2*)(rowc - 1024 + 2 * tid);
        xp4[ch] = *(const h2*)(rowc - 512 + 2 * tid);
      }
    }

    // ---- matvec: 4 cols x 32 u x 4 chains per thread ----
    half8 ha[4][4];
#pragma unroll
    for (int g = 0; g < 4; ++g)
#pragma unroll
      for (int k4 = 0; k4 < 4; ++k4)
        ha[g][k4] = *(const half8*)&hpk[g][p * 16 + k4 * 4];
    float acc[4][4];
#pragma unroll
    for (int j = 0; j < 4; ++j)
#pragma unroll
      for (int g = 0; g < 4; ++g) acc[j][g] = 0.f;
#pragma unroll
    for (int j = 0; j < 4; ++j) {
      const char* rowb = wlds + (cg * 4 + j) * 1024;
#pragma unroll
      for (int k4 = 0; k4 < 4; ++k4) {
        half8 w = *(const half8*)(rowb + ((unsigned)(p * 64 + k4 * 16) ^ cgx));
#pragma unroll
        for (int e = 0; e < 4; ++e) {
          h2 wp; wp[0] = w[2 * e]; wp[1] = w[2 * e + 1];
#pragma unroll
          for (int g = 0; g < 4; ++g) {
            h2 hp; hp[0] = ha[g][k4][2 * e]; hp[1] = ha[g][k4][2 * e + 1];
            acc[j][g] = dot2f(wp, hp, acc[j][g]);
          }
        }
      }
    }
#pragma unroll
    for (int j = 0; j < 4; ++j)
#pragma unroll
      for (int g = 0; g < 4; ++g) yred[p][g][cg * 4 + j] = acc[j][g];
    __syncthreads();

    // ---- reduce 16 partials; publish Vh words OR s0-partial scalar ----
    {
      const int ch = tid >> 6, c = tid & 63;
      float sum = 0.f;
#pragma unroll
      for (int p16 = 0; p16 < 16; ++p16) sum += yred[p16][ch][c];
      if (isV) {
        u64* dst = yV + (((size_t)grp * 2 + par) * 4 + ch) * 512 + s * 64 + c;
        __hip_atomic_store(dst, tagw | (u64)__float_as_uint(sum),
                           __ATOMIC_RELAXED, __HIP_MEMORY_SCOPE_AGENT);
      } else {
        const int u = (s - 8) * 64 + c;
        h2 hu = hpk[ch][u >> 1];
        float p0 = sum * (float)hu[u & 1];
#pragma unroll
        for (int off = 32; off > 0; off >>= 1) p0 += __shfl_down(p0, off);
        if (c == 0) {
          u64* dst = s0p + (((size_t)grp * 2 + par) * 4 + ch) * 8 + (s - 8);
          __hip_atomic_store(dst, tagw | (u64)__float_as_uint(p0),
                             __ATOMIC_RELAXED, __HIP_MEMORY_SCOPE_AGENT);
        }
      }
    }

    // ---- s1/s2 partials (h.G terms) — before poll, off critical path ----
    {
      float pr[8];
#pragma unroll
      for (int ch = 0; ch < 4; ++ch) {
        h2 hv = hpk[ch][tid];
        pr[2 * ch] = (float)gp4[ch][0] * (float)hv[0] +
                     (float)gp4[ch][1] * (float)hv[1];
        pr[2 * ch + 1] = (float)gc4[ch][0] * (float)hv[0] +
                         (float)gc4[ch][1] * (float)hv[1];
      }
#pragma unroll
      for (int off = 32; off > 0; off >>= 1)
#pragma unroll
        for (int i = 0; i < 8; ++i) pr[i] += __shfl_down(pr[i], off);
      if ((tid & 63) == 0) {
#pragma unroll
        for (int i = 0; i < 8; ++i) swred[tid >> 6][i] = pr[i];
      }
    }

    // ---- poll-gather: 8 Vh words; lanes<32 also one s0 partial ----
    const u64* yb = yV + (((size_t)grp * 2 + par) * 4) * 512;
    const u64* s0a = s0p + (((size_t)grp * 2 + par) * 4 + ((tid >> 3) & 3)) * 8 +
                     (tid & 7);
    u64 wv[8];
    u64 w8 = tagw;
    for (;;) {
      bool ok = true;
#pragma unroll
      for (int ch = 0; ch < 4; ++ch) {
        wv[2 * ch] = __hip_atomic_load(yb + ch * 512 + 2 * tid,
                                       __ATOMIC_RELAXED, __HIP_MEMORY_SCOPE_AGENT);
        wv[2 * ch + 1] = __hip_atomic_load(yb + ch * 512 + 2 * tid + 1,
                                           __ATOMIC_RELAXED, __HIP_MEMORY_SCOPE_AGENT);
        ok = ok && (wv[2 * ch] >= tagw) && (wv[2 * ch + 1] >= tagw);
      }
      if (tid < 32) {
        w8 = __hip_atomic_load(s0a, __ATOMIC_RELAXED, __HIP_MEMORY_SCOPE_AGENT);
        ok = ok && (w8 >= tagw);
      }
      if (ok) break;
      __builtin_amdgcn_s_sleep(1);
    }

    // ---- assemble s0 (lanes 0-31: 4 chains x 8 partials) ----
    if (tid < 32) {
      float sp = __uint_as_float((unsigned)w8);
      sp += __shfl_xor(sp, 1);
      sp += __shfl_xor(sp, 2);
      sp += __shfl_xor(sp, 4);
      if ((tid & 7) == 0) svals[tid >> 3] = sp;
    }
    __syncthreads();

    // ---- softmax + h update ----
#pragma unroll
    for (int ch = 0; ch < 4; ++ch) {
      float s0 = svals[ch] * scale;
      float s1 = (swred[0][2 * ch] + swred[1][2 * ch] + swred[2][2 * ch] +
                  swred[3][2 * ch]) * scale;
      float s2 = (swred[0][2 * ch + 1] + swred[1][2 * ch + 1] +
                  swred[2][2 * ch + 1] + swred[3][2 * ch + 1]) * scale;
      float mx = fmaxf(s0, fmaxf(s1, s2));
      float e0 = __expf(s0 - mx), e1 = __expf(s1 - mx), e2 = __expf(s2 - mx);
      float inv = 1.f / (e0 + e1 + e2);
      float a0 = e0 * inv, a1 = e1 * inv, a2 = e2 * inv;
      float v0 = __uint_as_float((unsigned)wv[2 * ch]);
      float v1 = __uint_as_float((unsigned)wv[2 * ch + 1]);
      float hn0 = a0 * v0 + a1 * (float)xp4[ch][0] + a2 * (float)xc4[ch][0];
      float hn1 = a0 * v1 + a1 * (float)xp4[ch][1] + a2 * (float)xc4[ch][1];
      h2 hn; hn[0] = (f16)hn0; hn[1] = (f16)hn1;
      hpk[ch][tid] = hn;
      if (t == T - 1 && s == 0) {
        out[((size_t)grp * 4 + ch) * 512 + 2 * tid] = hn0;
        out[((size_t)grp * 4 + ch) * 512 + 2 * tid + 1] = hn1;
      }
    }
    __syncthreads();
  }
}

extern "C" void kernel_launch(void* const* d_in, const int* in_sizes, int n_in,
                              void* d_out, int out_size, void* d_ws,
                              size_t ws_size, hipStream_t stream) {
  const float* x = (const float*)d_in[0];     // [64][512][512]
  const float* Wq = (const float*)d_in[1];
  const float* Wk = (const float*)d_in[2];
  const float* Wv = (const float*)d_in[3];
  const float* Wrec = (const float*)d_in[4];
  float* out = (float*)d_out;                 // [64][512]

  char* ws = (char*)d_ws;
  f16* GXV = (f16*)ws;                        // [32768][1024] f16 = 64 MiB
  f16* Wt = (f16*)(ws + 67108864);            // [1024][512] f16 = 1 MiB
  f16* Wrk = (f16*)(ws + 68157440);           // 512 KiB
  f16* Wrq = (f16*)(ws + 68681728);           // 512 KiB (ybuf overlays after use)
  f16* WgT = (f16*)(ws + 69206016);           // 512 KiB (ybuf overlays after use)
  u64* ybuf = (u64*)(ws + 68681728);          // 66560 u64 = 520 KiB

  // ---- weight combinations ----
  gemm128<AM_F32, BM_NN_F32, 0><<<16, 256, 0, stream>>>(Wrec, Wk, Wrk, 512, 512, 512, 0, 4);
  gemm128<AM_F32, BM_NN_F32, 0><<<16, 256, 0, stream>>>(Wrec, Wq, Wrq, 512, 512, 512, 0, 4);
  // Wt rows 0..511  = Wrv^T
  gemm128<AM_F32, BM_NN_F32, 1><<<16, 256, 0, stream>>>(Wrec, Wv, Wt, 512, 512, 512, 0, 4);
  // Wt rows 512..1023 = Wkq^T  (Wkq = Wrk@Wrq^T)
  gemm128<AM_F16, BM_BT_F16, 1><<<16, 256, 0, stream>>>(Wrk, Wrq, Wt, 512, 0, 512, 512, 4);
  // WgT = Wrk@Wq^T
  gemm128<AM_F16, BM_BT_F32, 0><<<16, 256, 0, stream>>>(Wrk, Wq, WgT, 512, 0, 512, 0, 4);
  // G and XV for all (b,t)
  gemm128<AM_F32, BM_BT_F16, 0><<<1024, 256, 0, stream>>>(x, WgT, GXV, 512, 0, 1024, 0, 4);
  gemm128<AM_F32, BM_NN_F32, 0><<<1024, 256, 0, stream>>>(x, Wv, GXV, 512, 512, 1024, 512, 4);

  // zero tagged buffer (after gemms that used the overlaid region)
  zero_ybuf<<<260, 256, 0, stream>>>(ybuf);

  // ---- sequential recurrence: cooperative, 256 WGs = 1 per CU ----
  const f16* WtC = Wt; const f16* GXVC = GXV;
  void* args[] = {(void*)&WtC, (void*)&GXVC, (void*)&ybuf, (void*)&out};
  dim3 grid(256), block(256);
  if (hipLaunchCooperativeKernel((const void*)seq_kernel, grid, block, args, 0,
                                 stream) != hipSuccess) {
    seq_kernel<<<grid, block, 0, stream>>>(WtC, GXVC, ybuf, out);
  }
}